// Round 1
// baseline (2807.379 us; speedup 1.0000x reference)
//
#include <hip/hip_runtime.h>
#include <math.h>

// SoftSkeletonize: 40 iterations of {erode; delta=relu(im-open(im)); skel+=relu(delta-skel*delta)}
// on 16 independent 1024x1024 fp32 planes.
//
// One fused kernel per iteration: load im tile + halo(3) into LDS, compute
// erode (=im_new), erode again, dilate 3x3 (=open(im_new)), then update skel
// in-place in d_out and write im_new to a ping-pong buffer in d_ws.
//
// Boundary semantics (from torch/JAX maxpool with -inf pad): out-of-image
// window entries are identity (+inf for min stages, -inf for the max stage).

#define HH 1024
#define WW 1024
#define TILE 32
#define NITER 40

__device__ __forceinline__ float fmin3(float a, float b, float c) { return fminf(a, fminf(b, c)); }
__device__ __forceinline__ float fmax3(float a, float b, float c) { return fmaxf(a, fmaxf(b, c)); }

// --- initial skeleton: skel = relu(img - dilate(erode(img))) ---
__global__ __launch_bounds__(256) void init_kernel(const float* __restrict__ img,
                                                   float* __restrict__ skel) {
    const int h0 = blockIdx.y * TILE;
    const int w0 = blockIdx.x * TILE;
    const size_t off = (size_t)blockIdx.z * (HH * WW);
    const float* base = img + off;
    float* sbase = skel + off;

    __shared__ float s_im[36][37];  // img over [-2..33]^2, +inf outside image
    __shared__ float s_e[34][35];   // erode(img) over [-1..32]^2, -inf outside image

    const int tid = threadIdx.x;
    for (int idx = tid; idx < 36 * 36; idx += 256) {
        int r = idx / 36, c = idx % 36;
        int gh = h0 + r - 2, gw = w0 + c - 2;
        float v = INFINITY;
        if (gh >= 0 && gh < HH && gw >= 0 && gw < WW) v = base[gh * WW + gw];
        s_im[r][c] = v;
    }
    __syncthreads();
    for (int idx = tid; idx < 34 * 34; idx += 256) {
        int r = idx / 34, c = idx % 34;
        int gh = h0 + r - 1, gw = w0 + c - 1;
        float v = -INFINITY;
        if (gh >= 0 && gh < HH && gw >= 0 && gw < WW) {
            int ir = r + 1, ic = c + 1;
            float p1 = fmin3(s_im[ir - 1][ic], s_im[ir][ic], s_im[ir + 1][ic]);
            float p2 = fmin3(s_im[ir][ic - 1], s_im[ir][ic], s_im[ir][ic + 1]);
            v = fminf(p1, p2);
        }
        s_e[r][c] = v;
    }
    __syncthreads();
    for (int idx = tid; idx < TILE * TILE; idx += 256) {
        int r = idx / TILE, c = idx % TILE;
        int er = r + 1, ec = c + 1;
        float m0 = fmax3(s_e[er - 1][ec - 1], s_e[er - 1][ec], s_e[er - 1][ec + 1]);
        float m1 = fmax3(s_e[er][ec - 1],     s_e[er][ec],     s_e[er][ec + 1]);
        float m2 = fmax3(s_e[er + 1][ec - 1], s_e[er + 1][ec], s_e[er + 1][ec + 1]);
        float open_v = fmax3(m0, m1, m2);
        float x = s_im[r + 2][c + 2];
        float d = x - open_v;
        sbase[(size_t)(h0 + r) * WW + (w0 + c)] = d > 0.f ? d : 0.f;
    }
}

// --- one iteration: im_dst = erode(im_src); skel += relu(delta - skel*delta) ---
__global__ __launch_bounds__(256) void step_kernel(const float* __restrict__ im_src,
                                                   float* __restrict__ im_dst,
                                                   float* __restrict__ skel) {
    const int h0 = blockIdx.y * TILE;
    const int w0 = blockIdx.x * TILE;
    const size_t off = (size_t)blockIdx.z * (HH * WW);
    const float* src = im_src + off;
    float* dst = im_dst + off;
    float* sk = skel + off;

    __shared__ float s_im[38][39];  // im over [-3..34]^2, +inf outside image
    __shared__ float s_e1[36][37];  // erode(im)=im_new over [-2..33]^2, +inf outside image
    __shared__ float s_e2[34][35];  // erode(im_new) over [-1..32]^2, -inf outside image

    const int tid = threadIdx.x;
    for (int idx = tid; idx < 38 * 38; idx += 256) {
        int r = idx / 38, c = idx % 38;
        int gh = h0 + r - 3, gw = w0 + c - 3;
        float v = INFINITY;
        if (gh >= 0 && gh < HH && gw >= 0 && gw < WW) v = src[gh * WW + gw];
        s_im[r][c] = v;
    }
    __syncthreads();
    for (int idx = tid; idx < 36 * 36; idx += 256) {
        int r = idx / 36, c = idx % 36;
        int gh = h0 + r - 2, gw = w0 + c - 2;
        float v = INFINITY;
        if (gh >= 0 && gh < HH && gw >= 0 && gw < WW) {
            int ir = r + 1, ic = c + 1;
            float p1 = fmin3(s_im[ir - 1][ic], s_im[ir][ic], s_im[ir + 1][ic]);
            float p2 = fmin3(s_im[ir][ic - 1], s_im[ir][ic], s_im[ir][ic + 1]);
            v = fminf(p1, p2);
        }
        s_e1[r][c] = v;
    }
    __syncthreads();
    for (int idx = tid; idx < 34 * 34; idx += 256) {
        int r = idx / 34, c = idx % 34;
        int gh = h0 + r - 1, gw = w0 + c - 1;
        float v = -INFINITY;
        if (gh >= 0 && gh < HH && gw >= 0 && gw < WW) {
            int er = r + 1, ec = c + 1;
            float p1 = fmin3(s_e1[er - 1][ec], s_e1[er][ec], s_e1[er + 1][ec]);
            float p2 = fmin3(s_e1[er][ec - 1], s_e1[er][ec], s_e1[er][ec + 1]);
            v = fminf(p1, p2);
        }
        s_e2[r][c] = v;
    }
    __syncthreads();
    for (int idx = tid; idx < TILE * TILE; idx += 256) {
        int r = idx / TILE, c = idx % TILE;
        float imn = s_e1[r + 2][c + 2];
        int er = r + 1, ec = c + 1;
        float m0 = fmax3(s_e2[er - 1][ec - 1], s_e2[er - 1][ec], s_e2[er - 1][ec + 1]);
        float m1 = fmax3(s_e2[er][ec - 1],     s_e2[er][ec],     s_e2[er][ec + 1]);
        float m2 = fmax3(s_e2[er + 1][ec - 1], s_e2[er + 1][ec], s_e2[er + 1][ec + 1]);
        float open_v = fmax3(m0, m1, m2);
        float delta = imn - open_v;
        delta = delta > 0.f ? delta : 0.f;
        size_t gi = (size_t)(h0 + r) * WW + (w0 + c);
        float s = sk[gi];
        float t = delta - s * delta;
        t = t > 0.f ? t : 0.f;
        sk[gi] = s + t;
        dst[gi] = imn;
    }
}

extern "C" void kernel_launch(void* const* d_in, const int* in_sizes, int n_in,
                              void* d_out, int out_size, void* d_ws, size_t ws_size,
                              hipStream_t stream) {
    const float* img = (const float*)d_in[0];
    float* skel = (float*)d_out;
    const int B = in_sizes[0] / (HH * WW);  // 16
    const size_t plane = (size_t)HH * WW;

    float* imA = (float*)d_ws;
    float* imB = imA + (size_t)B * plane;

    dim3 grid(WW / TILE, HH / TILE, B);
    dim3 block(256);

    init_kernel<<<grid, block, 0, stream>>>(img, skel);

    const float* src = img;
    float* bufs[2] = {imA, imB};
    for (int t = 0; t < NITER; ++t) {
        float* dst = bufs[t & 1];
        step_kernel<<<grid, block, 0, stream>>>(src, dst, skel);
        src = dst;
    }
}

// Round 2
// 2251.737 us; speedup vs baseline: 1.2468x; 1.2468x over previous
//
#include <hip/hip_runtime.h>
#include <math.h>

// SoftSkeletonize via the erosion-chain identity:
//   e_0 = img, e_{i+1} = erode(e_i)   (erode = 5-pt cross min, +inf pad)
//   delta_i = relu(e_i - dilate3x3(e_{i+1}))   (dilate pad = -inf)
//   skel: s = delta_0, then s += relu(delta_i - s*delta_i), i = 1..40
// (The erode inside soft_open IS the next iteration's im -> 1 erode + 1
//  dilate per step instead of 3 stencils; init folds into the chain.)
//
// Fused phases: K steps per launch (9,8,8,8,8). Per 64x64 tile stage
// e_{i0} + halo (12 top/left, 10 bottom/right) into LDS, chain in two
// ping-pong LDS buffers, skel tile in registers, write e_{i0+K} + skel.
// Interior tiles: float4-strip fast path (no predicates). Border tiles
// (within 12 of image edge): scalar checked path.

#define HH 1024
#define WW 1024
#define T 64
#define MT 12                    // top/left margin (>= K+1 = 10, 4-aligned)
#define MB 10                    // bottom/right margin
#define REG_H (MT + T + MB)      // 86 rows
#define STRIDE 88                // floats per LDS row (4-aligned, non-pow2)
#define NTHREADS 512

__device__ __forceinline__ float relu_(float x) { return x > 0.f ? x : 0.f; }
__device__ __forceinline__ float min3_(float a, float b, float c) { return fminf(a, fminf(b, c)); }
__device__ __forceinline__ float max3_(float a, float b, float c) { return fmaxf(a, fmaxf(b, c)); }

__global__ __launch_bounds__(NTHREADS, 1) void phase_kernel(
    const float* __restrict__ src, float* __restrict__ dst,
    float* __restrict__ skel, int K, int first, int last)
{
    __shared__ __align__(16) float Abuf[REG_H * STRIDE];
    __shared__ __align__(16) float Bbuf[REG_H * STRIDE];

    const int h0 = blockIdx.y * T;
    const int w0 = blockIdx.x * T;
    const size_t plane = (size_t)HH * WW;
    const float* sp = src + blockIdx.z * plane;
    float* skp = skel + blockIdx.z * plane;
    float* dp = dst ? dst + blockIdx.z * plane : nullptr;

    const int tid = threadIdx.x;
    const bool interior = (h0 >= MT) && (w0 >= MT) &&
                          (h0 + T + MB <= HH) && (w0 + T + MB <= WW);

    float* cur = Abuf;
    float* nxt = Bbuf;

    if (interior) {
        // ---- stage region: rows [h0-MT, h0+T+MB), cols [w0-MT, w0-MT+STRIDE)
        {
            const float* base = sp + (size_t)(h0 - MT) * WW + (w0 - MT);
            for (int idx = tid; idx < REG_H * (STRIDE / 4); idx += NTHREADS) {
                int r = idx / (STRIDE / 4);
                int q = idx - r * (STRIDE / 4);
                float4 v = *(const float4*)(base + (size_t)r * WW + 4 * q);
                *(float4*)&Abuf[r * STRIDE + 4 * q] = v;
            }
        }
        // skel accumulators: 1024 strips of 4, thread owns idx = tid + 512*k
        float4 s[2];
        if (!first) {
#pragma unroll
            for (int k = 0; k < 2; ++k) {
                int idx = tid + NTHREADS * k;
                int rr = idx >> 4, cc = (idx & 15) << 2;
                s[k] = *(const float4*)(skp + (size_t)(h0 + rr) * WW + (w0 + cc));
            }
        }
        __syncthreads();

        for (int j = 0; j < K; ++j) {
            // ---- erode cur -> nxt: rows [1,85), strips c0 = 0..84 step 4
            for (int idx = tid; idx < 84 * 22; idx += NTHREADS) {
                int r = 1 + idx / 22;
                int c0 = (idx - (r - 1) * 22) << 2;
                int o = r * STRIDE + c0;
                float4 up = *(const float4*)&cur[o - STRIDE];
                float4 mi = *(const float4*)&cur[o];
                float4 dn = *(const float4*)&cur[o + STRIDE];
                float lf = cur[o - 1], rt = cur[o + 4];
                float4 v;
                v.x = fminf(fminf(up.x, dn.x), min3_(lf,   mi.x, mi.y));
                v.y = fminf(fminf(up.y, dn.y), min3_(mi.x, mi.y, mi.z));
                v.z = fminf(fminf(up.z, dn.z), min3_(mi.y, mi.z, mi.w));
                v.w = fminf(fminf(up.w, dn.w), min3_(mi.z, mi.w, rt));
                *(float4*)&nxt[o] = v;
            }
            __syncthreads();
            // ---- dilate(nxt) + delta(cur) + skel update, central 64x64
#pragma unroll
            for (int k = 0; k < 2; ++k) {
                int idx = tid + NTHREADS * k;
                int r = MT + (idx >> 4);
                int c0 = MT + ((idx & 15) << 2);
                int o = r * STRIDE + c0;
                float4 tm = *(const float4*)&nxt[o - STRIDE];
                float tl = nxt[o - STRIDE - 1], tr = nxt[o - STRIDE + 4];
                float4 mm = *(const float4*)&nxt[o];
                float ml = nxt[o - 1], mr = nxt[o + 4];
                float4 bm = *(const float4*)&nxt[o + STRIDE];
                float bl = nxt[o + STRIDE - 1], br = nxt[o + STRIDE + 4];
                float4 th, mh, bh, d;
                th.x = max3_(tl,   tm.x, tm.y); th.y = max3_(tm.x, tm.y, tm.z);
                th.z = max3_(tm.y, tm.z, tm.w); th.w = max3_(tm.z, tm.w, tr);
                mh.x = max3_(ml,   mm.x, mm.y); mh.y = max3_(mm.x, mm.y, mm.z);
                mh.z = max3_(mm.y, mm.z, mm.w); mh.w = max3_(mm.z, mm.w, mr);
                bh.x = max3_(bl,   bm.x, bm.y); bh.y = max3_(bm.x, bm.y, bm.z);
                bh.z = max3_(bm.y, bm.z, bm.w); bh.w = max3_(bm.z, bm.w, br);
                d.x = max3_(th.x, mh.x, bh.x);
                d.y = max3_(th.y, mh.y, bh.y);
                d.z = max3_(th.z, mh.z, bh.z);
                d.w = max3_(th.w, mh.w, bh.w);
                float4 a = *(const float4*)&cur[o];
                float4 dl;
                dl.x = relu_(a.x - d.x); dl.y = relu_(a.y - d.y);
                dl.z = relu_(a.z - d.z); dl.w = relu_(a.w - d.w);
                if (first && j == 0) {
                    s[k] = dl;
                } else {
                    s[k].x += relu_(dl.x - s[k].x * dl.x);
                    s[k].y += relu_(dl.y - s[k].y * dl.y);
                    s[k].z += relu_(dl.z - s[k].z * dl.z);
                    s[k].w += relu_(dl.w - s[k].w * dl.w);
                }
            }
            __syncthreads();
            float* t = cur; cur = nxt; nxt = t;
        }
        // ---- write out skel + e_K central
#pragma unroll
        for (int k = 0; k < 2; ++k) {
            int idx = tid + NTHREADS * k;
            int rr = idx >> 4, cc = (idx & 15) << 2;
            *(float4*)(skp + (size_t)(h0 + rr) * WW + (w0 + cc)) = s[k];
            if (!last) {
                float4 v = *(const float4*)&cur[(MT + rr) * STRIDE + (MT + cc)];
                *(float4*)(dp + (size_t)(h0 + rr) * WW + (w0 + cc)) = v;
            }
        }
    } else {
        // ================= border slow path (60/256 tiles) =================
        for (int idx = tid; idx < REG_H * STRIDE; idx += NTHREADS) {
            int r = idx / STRIDE, c = idx - r * STRIDE;
            int gh = h0 - MT + r, gw = w0 - MT + c;
            float v = INFINITY;
            if (gh >= 0 && gh < HH && gw >= 0 && gw < WW) v = sp[(size_t)gh * WW + gw];
            Abuf[idx] = v;
        }
        float sreg[8];
        if (!first) {
#pragma unroll
            for (int k = 0; k < 8; ++k) {
                int idx = tid + NTHREADS * k;
                int rr = idx >> 6, cc = idx & 63;
                sreg[k] = skp[(size_t)(h0 + rr) * WW + (w0 + cc)];
            }
        }
        __syncthreads();

        for (int j = 0; j < K; ++j) {
            // erode: rows [1,85), cols [1,87); out-of-image stays +inf
            for (int idx = tid; idx < 84 * 86; idx += NTHREADS) {
                int r = 1 + idx / 86;
                int c = 1 + (idx - (r - 1) * 86);
                int gh = h0 - MT + r, gw = w0 - MT + c;
                float v = INFINITY;
                if (gh >= 0 && gh < HH && gw >= 0 && gw < WW) {
                    int o = r * STRIDE + c;
                    v = fminf(fminf(cur[o - STRIDE], cur[o + STRIDE]),
                              min3_(cur[o - 1], cur[o], cur[o + 1]));
                }
                nxt[r * STRIDE + c] = v;
            }
            __syncthreads();
            // dilate + update, central only; window cells clipped at image edge
#pragma unroll
            for (int k = 0; k < 8; ++k) {
                int idx = tid + NTHREADS * k;
                int rr = idx >> 6, cc = idx & 63;
                int r = MT + rr, c = MT + cc;
                int gh = h0 + rr, gw = w0 + cc;
                float m = -INFINITY;
#pragma unroll
                for (int dr = -1; dr <= 1; ++dr) {
                    int hr = gh + dr;
                    if (hr < 0 || hr >= HH) continue;
#pragma unroll
                    for (int dc = -1; dc <= 1; ++dc) {
                        int wc = gw + dc;
                        if (wc < 0 || wc >= WW) continue;
                        m = fmaxf(m, nxt[(r + dr) * STRIDE + (c + dc)]);
                    }
                }
                float dl = relu_(cur[r * STRIDE + c] - m);
                if (first && j == 0) sreg[k] = dl;
                else sreg[k] += relu_(dl - sreg[k] * dl);
            }
            __syncthreads();
            float* t = cur; cur = nxt; nxt = t;
        }
#pragma unroll
        for (int k = 0; k < 8; ++k) {
            int idx = tid + NTHREADS * k;
            int rr = idx >> 6, cc = idx & 63;
            skp[(size_t)(h0 + rr) * WW + (w0 + cc)] = sreg[k];
            if (!last) dp[(size_t)(h0 + rr) * WW + (w0 + cc)] = cur[(MT + rr) * STRIDE + (MT + cc)];
        }
    }
}

extern "C" void kernel_launch(void* const* d_in, const int* in_sizes, int n_in,
                              void* d_out, int out_size, void* d_ws, size_t ws_size,
                              hipStream_t stream) {
    const float* img = (const float*)d_in[0];
    float* skel = (float*)d_out;
    const int B = in_sizes[0] / (HH * WW);  // 16
    const size_t plane = (size_t)HH * WW;

    float* e0 = (float*)d_ws;
    float* e1 = e0 + (size_t)B * plane;

    dim3 grid(WW / T, HH / T, B);
    dim3 block(NTHREADS);

    // 41 chain steps total: deltas i = 0..40 (init + 40 iterations)
    const int Ks[5] = {9, 8, 8, 8, 8};
    const float* src = img;
    float* bufs[2] = {e0, e1};
    for (int p = 0; p < 5; ++p) {
        int first = (p == 0), last = (p == 4);
        float* dst = last ? nullptr : bufs[p & 1];
        phase_kernel<<<grid, block, 0, stream>>>(src, dst, skel, Ks[p], first, last);
        src = dst;
    }
}